// Round 2
// baseline (391.565 us; speedup 1.0000x reference)
//
#include <hip/hip_runtime.h>
#include <math.h>

#define DDIM 4096
#define NPAT 16384
#define THRESHOLD 0.8f

// Kernel 1: gated = sigmoid(query @ W^T + b)
// One 64-lane wave per output element d. W row d is contiguous (D floats).
// Each lane reads 16 float4 -> 64 floats; total 4096 = D. Fully coalesced:
// consecutive lanes hit consecutive float4s (1 KB contiguous per instruction).
__global__ __launch_bounds__(256) void gate_kernel(
    const float* __restrict__ query,
    const float* __restrict__ W,
    const float* __restrict__ b,
    float* __restrict__ gated)
{
    int gtid = blockIdx.x * blockDim.x + threadIdx.x;
    int row  = gtid >> 6;          // output element d
    int lane = threadIdx.x & 63;
    if (row >= DDIM) return;

    const float4* Wrow = (const float4*)(W + (size_t)row * DDIM);
    const float4* q4   = (const float4*)query;

    float sum = 0.0f;
#pragma unroll
    for (int i = 0; i < 16; ++i) {
        int idx = lane + i * 64;          // float4 index within row (0..1023)
        float4 w = Wrow[idx];
        float4 q = q4[idx];
        sum += w.x * q.x + w.y * q.y + w.z * q.z + w.w * q.w;
    }
#pragma unroll
    for (int off = 32; off > 0; off >>= 1)
        sum += __shfl_down(sum, off, 64);

    if (lane == 0) {
        float x = sum + b[row];
        gated[row] = 1.0f / (1.0f + __expf(-x));
    }
}

// Kernel 2: sims[n] = 1 - mean(|memory[n] - gated|); mask[n] = sims[n] >= 0.8
// One wave per pattern row (4 waves per 256-thread block, 4096 blocks).
// No __syncthreads, no LDS: pure shuffle reduction. 16 independent float4
// loads per lane for memory-level parallelism.
__global__ __launch_bounds__(256) void sims_kernel(
    const float* __restrict__ memory,
    const float* __restrict__ gated,
    float* __restrict__ sims,
    float* __restrict__ mask)
{
    int wid  = (blockIdx.x << 2) | (threadIdx.x >> 6);   // row index n
    int lane = threadIdx.x & 63;

    const float4* mrow = (const float4*)(memory + (size_t)wid * DDIM);
    const float4* g4   = (const float4*)gated;

    float sum = 0.0f;
#pragma unroll
    for (int i = 0; i < 16; ++i) {
        int idx = lane + i * 64;          // float4 index (0..1023), coalesced
        float4 m = mrow[idx];
        float4 g = g4[idx];
        sum += fabsf(m.x - g.x) + fabsf(m.y - g.y)
             + fabsf(m.z - g.z) + fabsf(m.w - g.w);
    }

#pragma unroll
    for (int off = 32; off > 0; off >>= 1)
        sum += __shfl_down(sum, off, 64);

    if (lane == 0) {
        float sim = 1.0f - sum * (1.0f / (float)DDIM);
        sims[wid] = sim;
        mask[wid] = (sim >= THRESHOLD) ? 1.0f : 0.0f;
    }
}

extern "C" void kernel_launch(void* const* d_in, const int* in_sizes, int n_in,
                              void* d_out, int out_size, void* d_ws, size_t ws_size,
                              hipStream_t stream) {
    const float* query  = (const float*)d_in[0];   // [1, D]
    const float* W      = (const float*)d_in[1];   // [D, D]
    const float* b      = (const float*)d_in[2];   // [D]
    const float* memory = (const float*)d_in[3];   // [N, D]

    float* gated = (float*)d_ws;                   // D floats scratch
    float* sims  = (float*)d_out;                  // first N floats
    float* mask  = (float*)d_out + NPAT;           // next N floats (0.0/1.0)

    // Kernel 1: D waves = D*64 threads -> 1024 blocks of 256
    gate_kernel<<<(DDIM * 64) / 256, 256, 0, stream>>>(query, W, b, gated);

    // Kernel 2: one wave per pattern row -> NPAT/4 blocks of 256
    sims_kernel<<<NPAT / 4, 256, 0, stream>>>(memory, gated, sims, mask);
}